// Round 1
// baseline (165.701 us; speedup 1.0000x reference)
//
#include <hip/hip_runtime.h>

// SFC model forward:
//   out[b] = bias_w[zero[b],0] + dot(user_w[user[b]], item_w[item[b]]) + freq_w[idx_emb[b], freq[b], 0]
// B = 2,097,152, EMB_DIM = 64.
// Memory-bound gather: 16 lanes cooperate per sample (lane loads float4 -> 256B
// coalesced row read), shfl_xor reduce over the 16-lane group.

#define EMB_DIM 64

__global__ __launch_bounds__(256) void sfc_fwd(
    const int* __restrict__ user, const int* __restrict__ item,
    const int* __restrict__ freq, const int* __restrict__ idx_emb,
    const int* __restrict__ zero, const float* __restrict__ bias_w,
    const float* __restrict__ user_w, const float* __restrict__ item_w,
    const float* __restrict__ freq_w, float* __restrict__ out, int B)
{
    const int group_in_block = threadIdx.x >> 4;   // 16 groups of 16 lanes per 256-thread block
    const int lane = threadIdx.x & 15;
    const int groups_per_grid = (gridDim.x * blockDim.x) >> 4;

    for (int s = blockIdx.x * 16 + group_in_block; s < B; s += groups_per_grid) {
        const int u_idx = user[s];
        const int i_idx = item[s];

        const float4 uv = *reinterpret_cast<const float4*>(
            user_w + (size_t)u_idx * EMB_DIM + lane * 4);
        const float4 vv = *reinterpret_cast<const float4*>(
            item_w + (size_t)i_idx * EMB_DIM + lane * 4);

        float d = uv.x * vv.x + uv.y * vv.y + uv.z * vv.z + uv.w * vv.w;

        // reduce across the 16-lane group (xor masks stay within the group)
        d += __shfl_xor(d, 1);
        d += __shfl_xor(d, 2);
        d += __shfl_xor(d, 4);
        d += __shfl_xor(d, 8);

        if (lane == 0) {
            const float bias = bias_w[zero[s]];                      // zero[s] == 0 always
            const float fe   = freq_w[idx_emb[s] * 32 + freq[s]];    // [50,32,1] table
            out[s] = bias + d + fe;
        }
    }
}

extern "C" void kernel_launch(void* const* d_in, const int* in_sizes, int n_in,
                              void* d_out, int out_size, void* d_ws, size_t ws_size,
                              hipStream_t stream) {
    const int B = in_sizes[0];
    const int*   user    = (const int*)d_in[0];
    const int*   item    = (const int*)d_in[1];
    const int*   freq    = (const int*)d_in[2];
    const int*   idx_emb = (const int*)d_in[3];
    const int*   zero    = (const int*)d_in[4];
    const float* bias_w  = (const float*)d_in[5];
    const float* user_w  = (const float*)d_in[6];
    const float* item_w  = (const float*)d_in[7];
    const float* freq_w  = (const float*)d_in[8];
    float* out = (float*)d_out;

    // 2048 blocks x 256 threads = 8 blocks/CU on 256 CUs, 32768 sample-groups,
    // grid-stride covers B = 2M samples in 64 iterations per group.
    const int blocks = 2048;
    sfc_fwd<<<blocks, 256, 0, stream>>>(user, item, freq, idx_emb, zero,
                                        bias_w, user_w, item_w, freq_w, out, B);
}